// Round 5
// baseline (7901.807 us; speedup 1.0000x reference)
//
#include <hip/hip_runtime.h>

#define S_LEN 256
#define BATCH 256
#define EDIM 512
#define HDIM 1024
#define LDS_BYTES 147456   // 128 KiB resident Wh (hk 16..31) + 16 KiB reduce buffer

typedef short short8 __attribute__((ext_vector_type(8)));
typedef float f32x4 __attribute__((ext_vector_type(4)));
typedef unsigned long long u64;
typedef unsigned short us;

__device__ __forceinline__ us f2bf(float f) {
  unsigned u = __float_as_uint(f);
  u = u + 0x7FFFu + ((u >> 16) & 1u);   // RNE
  return (us)(u >> 16);
}
__device__ __forceinline__ float bf2f(us s) {
  return __uint_as_float(((unsigned)s) << 16);
}
__device__ __forceinline__ float sigf(float x) { return 1.0f / (1.0f + __expf(-x)); }
__device__ __forceinline__ float tanh_(float x) { return 2.0f / (1.0f + __expf(-2.0f * x)) - 1.0f; }

#define MFMA(d, a, b) d = __builtin_amdgcn_mfma_f32_16x16x32_bf16(a, b, d, 0, 0, 0)

// Coherent (L3) 16B frag load: two 8B agent-scope relaxed atomic loads (R3-proven).
__device__ __forceinline__ short8 load_hfrag(const us* p) {
  union { u64 d[2]; short8 v; } u;
  u.d[0] = __hip_atomic_load((const u64*)p,       __ATOMIC_RELAXED, __HIP_MEMORY_SCOPE_AGENT);
  u.d[1] = __hip_atomic_load((const u64*)(p + 4), __ATOMIC_RELAXED, __HIP_MEMORY_SCOPE_AGENT);
  return u.v;
}
__device__ __forceinline__ short8 ldf(const us* p) {  // plain 16B frag load
  union { uint4 d; short8 v; } u;
  u.d = *(const uint4*)p;
  return u.v;
}

// All frag units are LANE-LINEAR: unit = 512 shorts (1 KB); lane l's 16 bytes at l*16.
// A-unit (16 batch rows x 32 k): elem (c=row, q=kchunk, e) at short (c + 16q)*8 + e.
// B-unit (16 n cols  x 32 k): elem (c=col, q, e) at short (c + 16q)*8 + e.

// ---------------- Phase 1: gather -> Xf[s][kt16][btile16][512] ----------------
__global__ void gather_embed(const int* __restrict__ inputs, const float* __restrict__ emb,
                             us* __restrict__ Xf) {
  int T = blockIdx.x * 256 + threadIdx.x;   // 1,048,576
  int kt = T & 15;
  int b  = (T >> 4) & 255;
  int s  = T >> 12;
  int vid = inputs[b * S_LEN + s];
  const float* src = emb + (size_t)vid * EDIM + kt * 32;
  int c = b & 15;
  us* ub = Xf + ((size_t)(s * 16 + kt) * 16 + (b >> 4)) * 512;
#pragma unroll
  for (int q = 0; q < 4; ++q) {
    float4 v0 = *(const float4*)(src + q * 8);
    float4 v1 = *(const float4*)(src + q * 8 + 4);
    us o[8] = { f2bf(v0.x), f2bf(v0.y), f2bf(v0.z), f2bf(v0.w),
                f2bf(v1.x), f2bf(v1.y), f2bf(v1.z), f2bf(v1.w) };
    *(uint4*)(ub + (size_t)(c + 16 * q) * 8) = *(const uint4*)o;
  }
}

// ---------------- Phase 2: pack W into lane-linear frag units ----------------
// Wxp[dir][jb][kit 0..15][t 0..7][512] ; Whp[dir][jb][hk 0..31][t][512]
// t = g*2 + h16 ; global col n = g*1024 + jb*32 + h16*16 + c ; k = kit*32 + q*8 + e.
__global__ void pack_w(const float* __restrict__ Wx_f, const float* __restrict__ Wh_f,
                       const float* __restrict__ Wx_b, const float* __restrict__ Wh_b,
                       us* __restrict__ Wxp, us* __restrict__ Whp) {
  int T = blockIdx.x * 256 + threadIdx.x;   // 1,572,864
  int c = T & 15;
  int q = (T >> 4) & 3;
  int t = (T >> 6) & 7;
  int r = T >> 9;                           // 0..3071
  int kit = r % 48;
  int jbd = r / 48;
  int jb  = jbd & 31;
  int dir = jbd >> 5;
  int g = t >> 1, h16 = t & 1;
  int n = g * 1024 + jb * 32 + h16 * 16 + c;
  const float* W; int k0;
  if (kit < 16) { W = dir ? Wx_b : Wx_f; k0 = kit * 32 + q * 8; }
  else          { W = dir ? Wh_b : Wh_f; k0 = (kit - 16) * 32 + q * 8; }
  us o[8];
#pragma unroll
  for (int e = 0; e < 8; ++e) o[e] = f2bf(W[(size_t)(k0 + e) * 4096 + n]);
  us* dst;
  if (kit < 16) dst = Wxp + (((size_t)(dir * 32 + jb) * 16 + kit) * 8 + t) * 512;
  else          dst = Whp + (((size_t)(dir * 32 + jb) * 32 + (kit - 16)) * 8 + t) * 512;
  *(uint4*)(dst + (size_t)(c + 16 * q) * 8) = *(const uint4*)o;
}

// ---------------- Phase 3: persistent BiLSTM, k-split, 8 waves/block ----------------
// 256 blocks x 512 thr (2 waves/SIMD). Block (dir, mq, jb): rows mq*64..+64, cols jb*32..+32/gate.
// 8 waves = kg (k-group) x (mw, nw). kg0: x-k 0..7 + h-k 0..15 (global Wh stream).
// kg1: x-k 8..15 + h-k 16..31 (LDS-resident Wh). Partials reduced via LDS; combine in kg0.
__global__ __launch_bounds__(512, 1) void lstm_main(
    const us* __restrict__ Xf,
    const us* __restrict__ Wxp,
    const us* __restrict__ Whp,
    const float* __restrict__ bias_f,
    const float* __restrict__ bias_b,
    us* __restrict__ Hf,                    // [buf2][dir2][kt32][btile16][512]
    unsigned int* __restrict__ slots)       // [group8][32][16]
{
  extern __shared__ __align__(16) unsigned char smem[];  // [0,128K): Wh hk16..31; [128K,144K): reduce

  const int bx   = blockIdx.x;
  const int xcd  = bx & 7;
  const int dir  = xcd >> 2;
  const int joct = xcd & 3;
  const int rr   = bx >> 3;           // 0..31
  const int jb   = joct * 8 + (rr & 7);
  const int mq   = rr >> 3;

  const int tid  = threadIdx.x;
  const int wave = tid >> 6;
  const int kg   = wave >> 2;         // k-group
  const int wl   = wave & 3;          // wave-tile id (R4's wave)
  const int lane = tid & 63;
  const int mw   = wl & 1;
  const int nw   = wl >> 1;
  const int c    = lane & 15;
  const int q    = lane >> 4;
  const int lofs = lane * 8;          // shorts (16 B)

  // one-time LDS fill: Whp units (dir,jb), hk 16..31 -> 8192 uint4, linear
  {
    const uint4* src = (const uint4*)(Whp + (((size_t)(dir * 32 + jb) * 32 + 16) * 8) * 512);
    for (int i = tid; i < 8192; i += 512) *(uint4*)(smem + (size_t)i * 16) = src[i];
  }
  const float* bias = dir ? bias_b : bias_f;
  const int j = jb * 32 + nw * 16 + c;
  float bg[4];
#pragma unroll
  for (int g = 0; g < 4; ++g) bg[g] = (kg == 0) ? bias[g * HDIM + j] : 0.f;
  __syncthreads();

  unsigned int* grp_slots = slots + (dir * 4 + mq) * (32 * 16);
  unsigned int* my_slot   = grp_slots + jb * 16;

  const int bt0 = mq * 4 + mw * 2;
  const us* xu_base = Xf + (size_t)bt0 * 512 + lofs;
  const us* wxu = Wxp + (((size_t)(dir * 32 + jb) * 16) * 8 + nw) * 512 + lofs;
  const us* whu = Whp + (((size_t)(dir * 32 + jb) * 32) * 8 + nw) * 512 + lofs;
  const int ldsofs = (nw * 512 + lane * 8) * 2;   // bytes; + g*2048 + tile*8192
  f32x4* red = (f32x4*)(smem + 131072);           // [g4][wl4][lane64] f32x4

  float c_reg[2][4] = {{0.f,0.f,0.f,0.f},{0.f,0.f,0.f,0.f}};

  for (int s = 0; s < S_LEN; ++s) {
    const int sx = dir ? (S_LEN - 1 - s) : s;
    const int p  = s & 1;

    f32x4 acc[2][4];
#pragma unroll
    for (int mt = 0; mt < 2; ++mt)
#pragma unroll
      for (int g = 0; g < 4; ++g)
        acc[mt][g] = (f32x4){bg[g], bg[g], bg[g], bg[g]};

    // ---- x-part (no h dependency; runs before the wait). kg0: k 0..7, kg1: k 8..15 ----
    {
      const us* xu = xu_base + (size_t)sx * (16 * 16 * 512) + (size_t)(kg * 8) * 8192;
      const us* wb0 = wxu + (size_t)(kg * 8) * 4096;
#pragma unroll
      for (int k = 0; k < 8; ++k) {
        short8 a0 = ldf(xu + (size_t)k * 8192);
        short8 a1 = ldf(xu + (size_t)k * 8192 + 512);
        const us* wb = wb0 + (size_t)k * 4096;
        short8 b0 = ldf(wb);
        short8 b1 = ldf(wb + 1024);
        short8 b2 = ldf(wb + 2048);
        short8 b3 = ldf(wb + 3072);
        MFMA(acc[0][0], a0, b0); MFMA(acc[0][1], a0, b1);
        MFMA(acc[0][2], a0, b2); MFMA(acc[0][3], a0, b3);
        MFMA(acc[1][0], a1, b0); MFMA(acc[1][1], a1, b1);
        MFMA(acc[1][2], a1, b2); MFMA(acc[1][3], a1, b3);
      }
    }

    // ---- wait for h_s: lanes 0..31 of wave 0 poll the 32 producer slots ----
    if (s > 0) {
      if (tid < 32) {
        const unsigned int* sl = grp_slots + tid * 16;
        for (;;) {
          unsigned v = __hip_atomic_load(sl, __ATOMIC_RELAXED, __HIP_MEMORY_SCOPE_AGENT);
          if (!__any(v < (unsigned)s)) break;
          __builtin_amdgcn_s_sleep(1);
        }
      }
      __syncthreads();
      asm volatile("" ::: "memory");
    }

    // ---- h-part: A coherent from Hf, prefetch depth 8. kg0 hk 0..15 (global B), kg1 hk 16..31 (LDS B) ----
    {
      const us* hu = Hf + (((size_t)(p * 2 + dir) * 32) * 16 + bt0) * 512 + lofs
                   + (size_t)(kg * 16) * 8192;
      short8 pa0[8], pa1[8];
#pragma unroll
      for (int i = 0; i < 8; ++i) {
        pa0[i] = load_hfrag(hu + (size_t)i * 8192);
        pa1[i] = load_hfrag(hu + (size_t)i * 8192 + 512);
      }
      if (kg == 0) {
#pragma unroll
        for (int k = 0; k < 8; ++k) {
          short8 a0 = pa0[k], a1 = pa1[k];
          pa0[k] = load_hfrag(hu + (size_t)(k + 8) * 8192);
          pa1[k] = load_hfrag(hu + (size_t)(k + 8) * 8192 + 512);
          const us* wb = whu + (size_t)k * 4096;
          short8 b0 = ldf(wb);
          short8 b1 = ldf(wb + 1024);
          short8 b2 = ldf(wb + 2048);
          short8 b3 = ldf(wb + 3072);
          MFMA(acc[0][0], a0, b0); MFMA(acc[0][1], a0, b1);
          MFMA(acc[0][2], a0, b2); MFMA(acc[0][3], a0, b3);
          MFMA(acc[1][0], a1, b0); MFMA(acc[1][1], a1, b1);
          MFMA(acc[1][2], a1, b2); MFMA(acc[1][3], a1, b3);
        }
#pragma unroll
        for (int k = 8; k < 16; ++k) {
          short8 a0 = pa0[k - 8], a1 = pa1[k - 8];
          const us* wb = whu + (size_t)k * 4096;
          short8 b0 = ldf(wb);
          short8 b1 = ldf(wb + 1024);
          short8 b2 = ldf(wb + 2048);
          short8 b3 = ldf(wb + 3072);
          MFMA(acc[0][0], a0, b0); MFMA(acc[0][1], a0, b1);
          MFMA(acc[0][2], a0, b2); MFMA(acc[0][3], a0, b3);
          MFMA(acc[1][0], a1, b0); MFMA(acc[1][1], a1, b1);
          MFMA(acc[1][2], a1, b2); MFMA(acc[1][3], a1, b3);
        }
      } else {
#pragma unroll
        for (int k = 0; k < 8; ++k) {
          short8 a0 = pa0[k], a1 = pa1[k];
          pa0[k] = load_hfrag(hu + (size_t)(k + 8) * 8192);
          pa1[k] = load_hfrag(hu + (size_t)(k + 8) * 8192 + 512);
          const unsigned char* lb = smem + (size_t)k * 8192 + ldsofs;
          short8 b0 = *(const short8*)(lb);
          short8 b1 = *(const short8*)(lb + 2048);
          short8 b2 = *(const short8*)(lb + 4096);
          short8 b3 = *(const short8*)(lb + 6144);
          MFMA(acc[0][0], a0, b0); MFMA(acc[0][1], a0, b1);
          MFMA(acc[0][2], a0, b2); MFMA(acc[0][3], a0, b3);
          MFMA(acc[1][0], a1, b0); MFMA(acc[1][1], a1, b1);
          MFMA(acc[1][2], a1, b2); MFMA(acc[1][3], a1, b3);
        }
#pragma unroll
        for (int k = 8; k < 16; ++k) {
          short8 a0 = pa0[k - 8], a1 = pa1[k - 8];
          const unsigned char* lb = smem + (size_t)k * 8192 + ldsofs;
          short8 b0 = *(const short8*)(lb);
          short8 b1 = *(const short8*)(lb + 2048);
          short8 b2 = *(const short8*)(lb + 4096);
          short8 b3 = *(const short8*)(lb + 6144);
          MFMA(acc[0][0], a0, b0); MFMA(acc[0][1], a0, b1);
          MFMA(acc[0][2], a0, b2); MFMA(acc[0][3], a0, b3);
          MFMA(acc[1][0], a1, b0); MFMA(acc[1][1], a1, b1);
          MFMA(acc[1][2], a1, b2); MFMA(acc[1][3], a1, b3);
        }
      }
    }

    // ---- cross-k-group reduction via LDS (two mt-rounds, 16 KiB buffer) ----
#pragma unroll
    for (int mt = 0; mt < 2; ++mt) {
      __syncthreads();
      if (kg == 1) {
#pragma unroll
        for (int g = 0; g < 4; ++g) red[(g * 4 + wl) * 64 + lane] = acc[mt][g];
      }
      __syncthreads();
      if (kg == 0) {
#pragma unroll
        for (int g = 0; g < 4; ++g) {
          f32x4 v = red[(g * 4 + wl) * 64 + lane];
          acc[mt][g][0] += v[0]; acc[mt][g][1] += v[1];
          acc[mt][g][2] += v[2]; acc[mt][g][3] += v[3];
        }
      }
    }

    // ---- gate combine in registers (kg0 only); coherent h stores ----
    if (kg == 0) {
      const int q2 = nw * 2 + (c >> 3);
      const int e2 = c & 7;
      const size_t ob = ((size_t)(((p ^ 1) * 2 + dir) * 32 + jb) * 16 + bt0) * 512;
#pragma unroll
      for (int mt = 0; mt < 2; ++mt) {
        us* hd = Hf + ob + (size_t)mt * 512 + (size_t)(16 * q2) * 8 + e2;
#pragma unroll
        for (int rg = 0; rg < 4; ++rg) {
          float gi = acc[mt][0][rg], gf = acc[mt][1][rg];
          float go = acc[mt][2][rg], gc = acc[mt][3][rg];
          float cn = sigf(gf) * c_reg[mt][rg] + sigf(gi) * tanh_(gc);
          c_reg[mt][rg] = cn;
          __hip_atomic_store(hd + (size_t)(q * 4 + rg) * 8, f2bf(sigf(go) * tanh_(cn)),
                             __ATOMIC_RELAXED, __HIP_MEMORY_SCOPE_AGENT);
        }
      }
    }
    asm volatile("s_waitcnt vmcnt(0)" ::: "memory");
    __syncthreads();
    if (tid == 0)
      __hip_atomic_store(my_slot, (unsigned)(s + 1), __ATOMIC_RELAXED, __HIP_MEMORY_SCOPE_AGENT);
  }
}

// ---------------- Phase 4: logits + softmax, one block per batch row ----------------
__global__ void final_softmax(const us* __restrict__ Hf,  // buf 0
                              const float* __restrict__ Whq,
                              const float* __restrict__ bq,
                              float* __restrict__ out) {
  __shared__ float red[4][10];
  const int b = blockIdx.x;
  const int tid = threadIdx.x;
  float acc[10];
#pragma unroll
  for (int qq = 0; qq < 10; ++qq) acc[qq] = 0.f;
#pragma unroll
  for (int u = 0; u < 4; ++u) {
    int j = tid * 4 + u;
    int kt = j >> 5, q2 = (j & 31) >> 3, e = j & 7;
    size_t idx = (((size_t)kt * 16 + (b >> 4)) * 512) + ((size_t)((b & 15) + 16 * q2)) * 8 + e;
    float xv = bf2f(Hf[idx]) + bf2f(Hf[(size_t)32 * 16 * 512 + idx]);
#pragma unroll
    for (int qq = 0; qq < 10; ++qq) acc[qq] += xv * Whq[j * 10 + qq];
  }
#pragma unroll
  for (int qq = 0; qq < 10; ++qq)
#pragma unroll
    for (int off = 32; off; off >>= 1) acc[qq] += __shfl_down(acc[qq], off, 64);
  if ((tid & 63) == 0)
#pragma unroll
    for (int qq = 0; qq < 10; ++qq) red[tid >> 6][qq] = acc[qq];
  __syncthreads();
  if (tid == 0) {
    float t[10];
#pragma unroll
    for (int qq = 0; qq < 10; ++qq)
      t[qq] = red[0][qq] + red[1][qq] + red[2][qq] + red[3][qq] + bq[qq];
    float mx = t[0];
#pragma unroll
    for (int qq = 1; qq < 10; ++qq) mx = fmaxf(mx, t[qq]);
    float sum = 0.f;
#pragma unroll
    for (int qq = 0; qq < 10; ++qq) { t[qq] = __expf(t[qq] - mx); sum += t[qq]; }
    float inv = 1.0f / sum;
#pragma unroll
    for (int qq = 0; qq < 10; ++qq) out[b * 10 + qq] = t[qq] * inv;
  }
}

extern "C" void kernel_launch(void* const* d_in, const int* in_sizes, int n_in,
                              void* d_out, int out_size, void* d_ws, size_t ws_size,
                              hipStream_t stream) {
  const int*   inputs = (const int*)d_in[0];
  const float* emb    = (const float*)d_in[1];
  const float* Wx_f   = (const float*)d_in[2];
  const float* Wh_f   = (const float*)d_in[3];
  const float* b_f    = (const float*)d_in[4];
  const float* Wx_b   = (const float*)d_in[5];
  const float* Wh_b   = (const float*)d_in[6];
  const float* b_b    = (const float*)d_in[7];
  const float* W_hq   = (const float*)d_in[8];
  const float* b_q    = (const float*)d_in[9];
  float* out = (float*)d_out;

  char* ws = (char*)d_ws;
  us* Xf  = (us*)ws;                              // 64 MiB
  us* Wxp = (us*)(ws + (64ull << 20));            //  8 MiB
  us* Whp = (us*)(ws + (72ull << 20));            // 16 MiB
  us* Hf  = (us*)(ws + (88ull << 20));            //  2 MiB
  unsigned int* slt = (unsigned int*)(ws + (90ull << 20));  // 16 KiB

  hipMemsetAsync(Hf, 0, (size_t)2 * 2 * 32 * 16 * 512 * sizeof(us), stream);
  hipMemsetAsync(slt, 0, 8 * 32 * 16 * sizeof(unsigned int), stream);

  gather_embed<<<4096, 256, 0, stream>>>(inputs, emb, Xf);
  pack_w<<<6144, 256, 0, stream>>>(Wx_f, Wh_f, Wx_b, Wh_b, Wxp, Whp);

  hipFuncSetAttribute((const void*)lstm_main,
                      hipFuncAttributeMaxDynamicSharedMemorySize, LDS_BYTES);

  const us* xf_p = Xf;
  const us* wxp_p = Wxp;
  const us* whp_p = Whp;
  const float* bf_p = b_f;
  const float* bb_p = b_b;
  us* hf_p = Hf;
  unsigned int* slt_p = slt;
  void* kargs[] = { (void*)&xf_p, (void*)&wxp_p, (void*)&whp_p, (void*)&bf_p,
                    (void*)&bb_p, (void*)&hf_p, (void*)&slt_p };
  hipLaunchCooperativeKernel((void*)lstm_main, dim3(256), dim3(512), kargs, LDS_BYTES, stream);

  // final h (after step 256) lives in buf 0
  final_softmax<<<256, 256, 0, stream>>>(Hf, W_hq, b_q, out);
}